// Round 11
// baseline (514.671 us; speedup 1.0000x reference)
//
#include <hip/hip_runtime.h>

#define OBS 8
#define PREDL 12
#define NCELL 19   // cell evals t=0..18; head(h_7..h_18) emitted at t=8..19

// LDS map (bytes)
#define W_OFF     0        // 65536: W_hh gates i,f (rows 0..255), 256B rows, swizzled(&15)
#define H_OFF     65536    // 32768: h, 128 rows x 256B, swizzled(&15)
#define RH_OFF    98304    // 32768: relu(h), same layout
#define XBUF_OFF  131072   // 1024: x [128 rows][2] f32
#define LDS_BYTES 132096

typedef short short8 __attribute__((ext_vector_type(8)));
typedef float f32x16 __attribute__((ext_vector_type(16)));
typedef float f32x4  __attribute__((ext_vector_type(4)));
struct U128 { unsigned a, b, c, d; };

__device__ __forceinline__ float sigm(float x) {
    return __builtin_amdgcn_rcpf(1.0f + __builtin_amdgcn_exp2f(x * -1.4426950408889634f));
}
__device__ __forceinline__ float tanh_(float x) {
    return __builtin_amdgcn_rcpf(1.0f + __builtin_amdgcn_exp2f(x * -2.8853900817779268f)) * 2.0f - 1.0f;
}
__device__ __forceinline__ unsigned f2bf(float f) {
    unsigned u = __builtin_bit_cast(unsigned, f);
    u += 0x7fffu + ((u >> 16) & 1u);   // RNE
    return u >> 16;
}
__device__ __forceinline__ unsigned cvtpk(float lo, float hi) {
    unsigned r;
    asm("v_cvt_pk_bf16_f32 %0, %1, %2" : "=v"(r) : "v"(lo), "v"(hi));
    return r;
}

// prep: W_hh gates g,o (rows 256..511) -> bf16 B-fragment layout (32x32x16).
// dst[G*32768 + (ks*256 + gcol*2 + hf)*16] = W[256+G*128+gcol][ks*16+hf*8 .. +8]
__global__ void prep_go(const float* __restrict__ W_hh, char* __restrict__ wsg)
{
    int idx = blockIdx.x * 256 + threadIdx.x;   // 4096
    int G = idx >> 11, ks = (idx >> 8) & 7, gcol = (idx >> 1) & 127, hf = idx & 1;
    const float* src = W_hh + (size_t)(256 + G * 128 + gcol) * 128 + ks * 16 + hf * 8;
    float4 u = *(const float4*)src;
    float4 v = *(const float4*)(src + 4);
    U128 pk = { f2bf(u.x) | (f2bf(u.y) << 16), f2bf(u.z) | (f2bf(u.w) << 16),
                f2bf(v.x) | (f2bf(v.y) << 16), f2bf(v.z) | (f2bf(v.w) << 16) };
    *(U128*)(wsg + (size_t)(G * 2048 + (idx & 2047)) * 16) = pk;
}

__global__ __attribute__((amdgpu_waves_per_eu(4, 4))) __launch_bounds__(1024)
void lstm_persist(const float* __restrict__ traj_in, const float* __restrict__ traj_gt,
                  const float* __restrict__ W_ih, const float* __restrict__ W_hh,
                  const float* __restrict__ b_ih, const float* __restrict__ b_hh,
                  const float* __restrict__ W_last, const float* __restrict__ b_last,
                  float* __restrict__ out, const char* __restrict__ wsg,
                  float* __restrict__ wsloss)
{
    extern __shared__ char smem[];
    const int tid  = threadIdx.x;
    const int lane = tid & 63;
    const int wave = tid >> 6;          // 0..15
    const int l31  = lane & 31;
    const int half = lane >> 5;
    const int l15  = lane & 15;
    const int q    = lane >> 4;         // 0..3 (16x16 shapes)
    const int sw   = (l31 & 15) << 4;
    const int wm   = wave >> 2;         // rows wm*32..+31
    const int wc   = wave & 3;          // gate cols wc*32..+31
    const int col0 = wc * 32;
    const int rbase = blockIdx.x * 128;
    const int myrow = wm * 32 + l31;

    // ---- stage W_hh gates i,f (rows 0..255) -> LDS bf16 swizzled(&15)
    for (int it = 0; it < 8; ++it) {
        int i = it * 1024 + tid;           // 8192 float4 items
        int n = i >> 5, c4 = i & 31;
        const float4 w = *(const float4*)(W_hh + (size_t)n * 128 + c4 * 4);
        uint2 pk = { f2bf(w.x) | (f2bf(w.y) << 16), f2bf(w.z) | (f2bf(w.w) << 16) };
        *(uint2*)(smem + W_OFF + n * 256 + ((c4 * 8) ^ ((n & 15) << 4))) = pk;
    }
    // ---- zero h (reluh fully written at t=7 before first read at t=8)
    for (int i = 0; i < 8; ++i)
        *(unsigned*)(smem + H_OFF + (tid + i * 1024) * 4) = 0u;

    // ---- ext B-fragments (x-weights + bias), 16 VGPRs
    short8 Ee[4];
    #pragma unroll
    for (int gg = 0; gg < 4; ++gg) {
        U128 v = { 0u, 0u, 0u, 0u };
        if (half == 0) {
            int n = gg * 128 + col0 + l31;
            float2 wi = *(const float2*)(W_ih + n * 2);
            float bsum = b_ih[n] + b_hh[n];
            v.a = f2bf(wi.x) | (f2bf(wi.y) << 16);
            v.b = f2bf(bsum);
        }
        Ee[gg] = __builtin_bit_cast(short8, v);
    }
    // ---- head B-fragments (W_last as 16x16x32 B), 16 VGPRs
    short8 Blast[4];
    #pragma unroll
    for (int ks = 0; ks < 4; ++ks) {
        U128 v = { 0u, 0u, 0u, 0u };
        if (l15 < 2) {
            const float* p = W_last + l15 * 128 + ks * 32 + q * 8;
            float4 u = *(const float4*)p;
            float4 w = *(const float4*)(p + 4);
            v.a = f2bf(u.x) | (f2bf(u.y) << 16); v.b = f2bf(u.z) | (f2bf(u.w) << 16);
            v.c = f2bf(w.x) | (f2bf(w.y) << 16); v.d = f2bf(w.z) | (f2bf(w.w) << 16);
        }
        Blast[ks] = __builtin_bit_cast(short8, v);
    }
    const float bl0 = b_last[0], bl1 = b_last[1];

    __syncthreads();

    float c_[16];
    #pragma unroll
    for (int r = 0; r < 16; ++r) c_[r] = 0.f;
    float lossAcc = 0.f;

    for (int t = 0; t <= NCELL; ++t) {
        // ======== phase 1 (pre-B1): head MFMA -> xbuf + emit (even waves, t>=8)
        if (t >= OBS && !(wave & 1)) {
            const int rt = wave >> 1;            // 0..7: rows rt*16..+15
            f32x4 hd{};
            #pragma unroll
            for (int ks = 0; ks < 4; ++ks) {
                short8 ar = *(const short8*)(smem + RH_OFF + (rt * 16 + l15) * 256 +
                                             ((ks * 64 + q * 16) ^ (l15 << 4)));
                hd = __builtin_amdgcn_mfma_f32_16x16x32_bf16(ar, Blast[ks], hd, 0, 0, 0);
            }
            if (l15 < 2) {
                const float bl = l15 ? bl1 : bl0;
                const int p = t - OBS;           // 0..11
                #pragma unroll
                for (int r = 0; r < 4; ++r) {
                    int row = rt * 16 + q * 4 + r;
                    float val = hd[r] + bl;
                    *(float*)(smem + XBUF_OFF + row * 8 + l15 * 4) = val;
                    size_t og = ((size_t)(rbase + row) * PREDL + p) * 2 + l15;
                    out[og] = val;
                    float d = val - traj_gt[og];
                    lossAcc = fmaf(d, d, lossAcc);
                }
            }
        }
        if (t == NCELL) break;                   // t==19: emission-only iteration

        float2 xx = make_float2(0.f, 0.f);
        if (half == 0 && t < OBS)
            xx = *(const float2*)(traj_in + ((size_t)(rbase + myrow) * OBS + t) * 2);

        short8 a[8];
        #pragma unroll
        for (int ks = 0; ks < 8; ++ks)
            a[ks] = *(const short8*)(smem + H_OFF + myrow * 256 + ((ks * 32 + half * 16) ^ sw));

        __syncthreads();   // B1: xbuf ready, h reads complete

        // ======== gates: i,f from LDS; g,o streamed from L2-hot fragments
        if (half == 0 && t >= OBS)
            xx = *(const float2*)(smem + XBUF_OFF + myrow * 8);
        unsigned xv = (half == 0) ? cvtpk(xx.x, xx.y) : 0u;
        U128 ax = { xv, (half == 0) ? 0x00003F80u : 0u, 0u, 0u };
        short8 aext = __builtin_bit_cast(short8, ax);

        f32x16 ac0{}, ac1{}, ac2{}, ac3{};
        ac0 = __builtin_amdgcn_mfma_f32_32x32x16_bf16(aext, Ee[0], ac0, 0, 0, 0);
        ac1 = __builtin_amdgcn_mfma_f32_32x32x16_bf16(aext, Ee[1], ac1, 0, 0, 0);
        ac2 = __builtin_amdgcn_mfma_f32_32x32x16_bf16(aext, Ee[2], ac2, 0, 0, 0);
        ac3 = __builtin_amdgcn_mfma_f32_32x32x16_bf16(aext, Ee[3], ac3, 0, 0, 0);
        #pragma unroll
        for (int ks = 0; ks < 8; ++ks) {
            const int bb = (ks * 32 + half * 16) ^ sw;
            const char* wb = smem + W_OFF + (col0 + l31) * 256 + bb;
            short8 bi  = *(const short8*)(wb);
            short8 bf_ = *(const short8*)(wb + 128 * 256);
            const char* gb = wsg + (size_t)(ks * 256 + (col0 + l31) * 2 + half) * 16;
            short8 bg  = *(const short8*)(gb);
            short8 bo  = *(const short8*)(gb + 32768);
            ac0 = __builtin_amdgcn_mfma_f32_32x32x16_bf16(a[ks], bi,  ac0, 0, 0, 0);
            ac1 = __builtin_amdgcn_mfma_f32_32x32x16_bf16(a[ks], bf_, ac1, 0, 0, 0);
            ac2 = __builtin_amdgcn_mfma_f32_32x32x16_bf16(a[ks], bg,  ac2, 0, 0, 0);
            ac3 = __builtin_amdgcn_mfma_f32_32x32x16_bf16(a[ks], bo,  ac3, 0, 0, 0);
        }

        // ======== elementwise + packed h/reluh writes
        const bool doRelu = (t >= OBS - 1);
        #pragma unroll
        for (int r = 0; r < 16; ++r) {
            float iv = sigm(ac0[r]);
            float fv = sigm(ac1[r]);
            float gv = tanh_(ac2[r]);
            float ov = sigm(ac3[r]);
            float cv = fmaf(fv, c_[r], iv * gv);
            c_[r] = cv;
            float hv = ov * tanh_(cv);
            const int row  = (r & 3) + 8 * (r >> 2) + 4 * half;   // 0..31
            const int arow = wm * 32 + row;
            const int baddr = ((col0 + l31) * 2) ^ ((row & 15) << 4);   // FIX: mask to 4 bits
            float hn = __builtin_bit_cast(float,
                __builtin_amdgcn_update_dpp(0, __builtin_bit_cast(int, hv), 0xB1, 0xf, 0xf, true));
            unsigned hp = cvtpk(hv, hn);
            if (!(l31 & 1))
                *(unsigned*)(smem + H_OFF + arow * 256 + baddr) = hp;
            if (doRelu) {
                float rl = fmaxf(hv, 0.f);
                float rn = fmaxf(hn, 0.f);
                unsigned rp = cvtpk(rl, rn);
                if (!(l31 & 1))
                    *(unsigned*)(smem + RH_OFF + arow * 256 + baddr) = rp;
            }
        }
        __syncthreads();   // B2: h/reluh visible for next step
    }

    // ---- block loss partials
    #pragma unroll
    for (int s = 1; s < 64; s <<= 1) lossAcc += __shfl_xor(lossAcc, s, 64);
    if (lane == 0) wsloss[blockIdx.x * 16 + wave] = lossAcc;
}

__global__ void loss_reduce(const float* __restrict__ wsloss, float* __restrict__ out,
                            int npart, int nelem)
{
    __shared__ float sacc[4];
    int tid = threadIdx.x;   // 256
    float v = 0.f;
    for (int j = tid; j < npart; j += 256) v += wsloss[j];   // fixed order per lane
    #pragma unroll
    for (int s = 1; s < 64; s <<= 1) v += __shfl_xor(v, s, 64);
    if ((tid & 63) == 0) sacc[tid >> 6] = v;
    __syncthreads();
    if (tid == 0) out[nelem] = (sacc[0] + sacc[1] + sacc[2] + sacc[3]) / (float)nelem;
}

extern "C" void kernel_launch(void* const* d_in, const int* in_sizes, int n_in,
                              void* d_out, int out_size, void* d_ws, size_t ws_size,
                              hipStream_t stream)
{
    const float* traj_in = (const float*)d_in[0];
    const float* traj_gt = (const float*)d_in[1];
    const float* W_ih    = (const float*)d_in[2];
    const float* W_hh    = (const float*)d_in[3];
    const float* b_ih    = (const float*)d_in[4];
    const float* b_hh    = (const float*)d_in[5];
    const float* W_last  = (const float*)d_in[6];
    const float* b_last  = (const float*)d_in[7];
    float* out = (float*)d_out;
    char*  wsg    = (char*)d_ws;                      // 64 KB gate-g,o fragments
    float* wsloss = (float*)((char*)d_ws + 65536);    // 4096 partials

    const int B      = in_sizes[0] / (OBS * 2);   // 32768
    const int blocks = B / 128;                    // 256

    prep_go<<<16, 256, 0, stream>>>(W_hh, wsg);
    lstm_persist<<<blocks, 1024, LDS_BYTES, stream>>>(traj_in, traj_gt, W_ih, W_hh,
                                                      b_ih, b_hh, W_last, b_last,
                                                      out, wsg, wsloss);
    loss_reduce<<<1, 256, 0, stream>>>(wsloss, out, blocks * 16, out_size - 1);
}

// Round 12
// 188.679 us; speedup vs baseline: 2.7278x; 2.7278x over previous
//
#include <hip/hip_runtime.h>

#define OBS 8
#define PREDL 12
#define NCELL 19   // cell evals t=0..18; emissions p=0..10 in-loop (t=8..18), p=11 in tail

// LDS map (bytes)
#define W_OFF     0        // 98304: W_hh gates i,f,g (rows 0..383), 256B rows, swizzled(&15)
#define H_OFF     98304    // 2 x 16384: h double buffer, 64 rows x 256B, swizzled(&15)
#define SCR_OFF   131072   // 2 x 2048: head partials [parity][wc][64 rows][2] f32
#define RED_OFF   135168   // 64: loss partials
#define LDS_BYTES 135232

typedef short short8 __attribute__((ext_vector_type(8)));
typedef float f32x16 __attribute__((ext_vector_type(16)));
struct U128 { unsigned a, b, c, d; };

__device__ __forceinline__ float sigm(float x) {
    return __builtin_amdgcn_rcpf(1.0f + __builtin_amdgcn_exp2f(x * -1.4426950408889634f));
}
__device__ __forceinline__ float tanh_(float x) {
    return __builtin_amdgcn_rcpf(1.0f + __builtin_amdgcn_exp2f(x * -2.8853900817779268f)) * 2.0f - 1.0f;
}
__device__ __forceinline__ unsigned f2bf(float f) {
    unsigned u = __builtin_bit_cast(unsigned, f);
    u += 0x7fffu + ((u >> 16) & 1u);   // RNE
    return u >> 16;
}
__device__ __forceinline__ unsigned cvtpk(float lo, float hi) {
    unsigned r;
    asm("v_cvt_pk_bf16_f32 %0, %1, %2" : "=v"(r) : "v"(lo), "v"(hi));
    return r;
}
#define DPP_ADD(v, ctrl) \
    v += __builtin_bit_cast(float, __builtin_amdgcn_update_dpp(0, __builtin_bit_cast(int, v), ctrl, 0xf, 0xf, true))

__global__ __attribute__((amdgpu_waves_per_eu(2, 2))) __launch_bounds__(512)
void lstm_persist(const float* __restrict__ traj_in, const float* __restrict__ traj_gt,
                  const float* __restrict__ W_ih, const float* __restrict__ W_hh,
                  const float* __restrict__ b_ih, const float* __restrict__ b_hh,
                  const float* __restrict__ W_last, const float* __restrict__ b_last,
                  float* __restrict__ out, float* __restrict__ wsloss)
{
    extern __shared__ char smem[];
    const int tid  = threadIdx.x;
    const int lane = tid & 63;
    const int wave = tid >> 6;          // 0..7
    const int l31  = lane & 31;
    const int half = lane >> 5;
    const int sw   = (l31 & 15) << 4;
    const int wm   = wave >> 2;         // rows wm*32..+31
    const int wc   = wave & 3;          // gate cols wc*32..+31
    const int col0 = wc * 32;
    const int rbase = blockIdx.x * 64;
    const int myrow = wm * 32 + l31;

    // ---- stage W_hh gates i,f,g (rows 0..383) -> LDS bf16, swizzled(&15)
    for (int it = 0; it < 24; ++it) {
        int i = it * 512 + tid;            // 12288 float4 items
        int n = i >> 5, c4 = i & 31;
        const float4 w = *(const float4*)(W_hh + (size_t)n * 128 + c4 * 4);
        uint2 pk = { f2bf(w.x) | (f2bf(w.y) << 16), f2bf(w.z) | (f2bf(w.w) << 16) };
        *(uint2*)(smem + W_OFF + n * 256 + ((c4 * 8) ^ ((n & 15) << 4))) = pk;
    }
    // ---- zero h (both parities)
    for (int i = 0; i < 16; ++i)
        *(unsigned*)(smem + H_OFF + (tid + i * 512) * 4) = 0u;

    // ---- ext B-fragments (x-weights + bias), 16 VGPRs
    short8 Ee[4];
    #pragma unroll
    for (int gg = 0; gg < 4; ++gg) {
        U128 v = { 0u, 0u, 0u, 0u };
        if (half == 0) {
            int n = gg * 128 + col0 + l31;
            float2 wi = *(const float2*)(W_ih + n * 2);
            float bsum = b_ih[n] + b_hh[n];
            v.a = f2bf(wi.x) | (f2bf(wi.y) << 16);
            v.b = f2bf(bsum);
        }
        Ee[gg] = __builtin_bit_cast(short8, v);
    }
    // ---- gate-o B-fragments -> 32 persistent VGPRs (loop-invariant, one-time load)
    short8 Bo[8];
    #pragma unroll
    for (int ks = 0; ks < 8; ++ks) {
        const float* p = W_hh + (size_t)(384 + col0 + l31) * 128 + ks * 16 + half * 8;
        float4 u = *(const float4*)p;
        float4 v = *(const float4*)(p + 4);
        U128 q = { f2bf(u.x) | (f2bf(u.y) << 16), f2bf(u.z) | (f2bf(u.w) << 16),
                   f2bf(v.x) | (f2bf(v.y) << 16), f2bf(v.z) | (f2bf(v.w) << 16) };
        Bo[ks] = __builtin_bit_cast(short8, q);
    }
    const float wl0 = W_last[col0 + l31];
    const float wl1 = W_last[128 + col0 + l31];
    const float bl0 = b_last[0], bl1 = b_last[1];

    __syncthreads();

    float c_[16];
    #pragma unroll
    for (int r = 0; r < 16; ++r) c_[r] = 0.f;
    float lossAcc = 0.f;

    for (int t = 0; t < NCELL; ++t) {
        const int hcur = H_OFF + (t & 1) * 16384;
        const int hnxt = H_OFF + ((t & 1) ^ 1) * 16384;
        const int scrR = SCR_OFF + ((t & 1) ^ 1) * 2048;   // written at t-1
        const int scrW = SCR_OFF + (t & 1) * 2048;         // read at t+1

        // ---- x for this step (half==0 lanes own row myrow); emit p=t-8 for t>=8
        float2 xx = make_float2(0.f, 0.f);
        if (half == 0) {
            if (t < OBS) {
                xx = *(const float2*)(traj_in + ((size_t)(rbase + myrow) * OBS + t) * 2);
            } else {
                const char* base = smem + scrR + myrow * 8;
                float2 s0 = *(const float2*)(base);
                float2 s1 = *(const float2*)(base + 512);
                float2 s2 = *(const float2*)(base + 1024);
                float2 s3 = *(const float2*)(base + 1536);
                xx.x = ((s0.x + s1.x) + (s2.x + s3.x)) + bl0;
                xx.y = ((s0.y + s1.y) + (s2.y + s3.y)) + bl1;
                if (wc == 0) {
                    size_t og = ((size_t)(rbase + myrow) * PREDL + (t - OBS)) * 2;
                    float2 gt = *(const float2*)(traj_gt + og);
                    *(float2*)(out + og) = xx;
                    float d0 = xx.x - gt.x, d1 = xx.y - gt.y;
                    lossAcc = fmaf(d0, d0, fmaf(d1, d1, lossAcc));
                }
            }
        }

        // ---- A fragments from h[cur] (parity-safe, no barrier needed)
        short8 a[8];
        #pragma unroll
        for (int ks = 0; ks < 8; ++ks)
            a[ks] = *(const short8*)(smem + hcur + myrow * 256 + ((ks * 32 + half * 16) ^ sw));

        // ---- gates: K-ext (x,bias) + K=128 over i,f,g (LDS) and o (registers)
        unsigned xv = (half == 0) ? cvtpk(xx.x, xx.y) : 0u;
        U128 ax = { xv, (half == 0) ? 0x00003F80u : 0u, 0u, 0u };
        short8 aext = __builtin_bit_cast(short8, ax);

        f32x16 ac0{}, ac1{}, ac2{}, ac3{};
        ac0 = __builtin_amdgcn_mfma_f32_32x32x16_bf16(aext, Ee[0], ac0, 0, 0, 0);
        ac1 = __builtin_amdgcn_mfma_f32_32x32x16_bf16(aext, Ee[1], ac1, 0, 0, 0);
        ac2 = __builtin_amdgcn_mfma_f32_32x32x16_bf16(aext, Ee[2], ac2, 0, 0, 0);
        ac3 = __builtin_amdgcn_mfma_f32_32x32x16_bf16(aext, Ee[3], ac3, 0, 0, 0);
        #pragma unroll
        for (int ks = 0; ks < 8; ++ks) {
            const int bb = (ks * 32 + half * 16) ^ sw;
            const char* wb = smem + W_OFF + (col0 + l31) * 256 + bb;
            short8 bi  = *(const short8*)(wb);
            short8 bf_ = *(const short8*)(wb + 128 * 256);
            short8 bg  = *(const short8*)(wb + 256 * 256);
            ac0 = __builtin_amdgcn_mfma_f32_32x32x16_bf16(a[ks], bi,     ac0, 0, 0, 0);
            ac1 = __builtin_amdgcn_mfma_f32_32x32x16_bf16(a[ks], bf_,    ac1, 0, 0, 0);
            ac2 = __builtin_amdgcn_mfma_f32_32x32x16_bf16(a[ks], bg,     ac2, 0, 0, 0);
            ac3 = __builtin_amdgcn_mfma_f32_32x32x16_bf16(a[ks], Bo[ks], ac3, 0, 0, 0);
        }

        // ---- elementwise + packed h write + DPP head partials
        const bool doHead = (t >= OBS - 1);
        #pragma unroll
        for (int r = 0; r < 16; ++r) {
            float iv = sigm(ac0[r]);
            float fv = sigm(ac1[r]);
            float gv = tanh_(ac2[r]);
            float ov = sigm(ac3[r]);
            float cv = fmaf(fv, c_[r], iv * gv);
            c_[r] = cv;
            float hv = ov * tanh_(cv);
            const int row  = (r & 3) + 8 * (r >> 2) + 4 * half;   // 0..31
            const int arow = wm * 32 + row;
            const int baddr = ((col0 + l31) * 2) ^ ((row & 15) << 4);
            float hn = __builtin_bit_cast(float,
                __builtin_amdgcn_update_dpp(0, __builtin_bit_cast(int, hv), 0xB1, 0xf, 0xf, true));
            unsigned hp = cvtpk(hv, hn);
            if (!(l31 & 1))
                *(unsigned*)(smem + hnxt + arow * 256 + baddr) = hp;
            if (doHead) {
                float rl = fmaxf(hv, 0.f);
                float v0 = rl * wl0, v1 = rl * wl1;
                DPP_ADD(v0, 0x111); DPP_ADD(v0, 0x112); DPP_ADD(v0, 0x114);
                DPP_ADD(v0, 0x118); DPP_ADD(v0, 0x142);
                DPP_ADD(v1, 0x111); DPP_ADD(v1, 0x112); DPP_ADD(v1, 0x114);
                DPP_ADD(v1, 0x118); DPP_ADD(v1, 0x142);
                if (l31 == 31)
                    *(float2*)(smem + scrW + wc * 512 + arow * 8) = make_float2(v0, v1);
            }
        }
        __syncthreads();   // single barrier: h[nxt]/scr[W] visible for t+1
    }

    // ---- tail: emit p = 11 from partials written at t=18 (parity 0)
    if (half == 0 && wc == 0) {
        const char* base = smem + SCR_OFF + myrow * 8;
        float2 s0 = *(const float2*)(base);
        float2 s1 = *(const float2*)(base + 512);
        float2 s2 = *(const float2*)(base + 1024);
        float2 s3 = *(const float2*)(base + 1536);
        float o0 = ((s0.x + s1.x) + (s2.x + s3.x)) + bl0;
        float o1 = ((s0.y + s1.y) + (s2.y + s3.y)) + bl1;
        size_t og = ((size_t)(rbase + myrow) * PREDL + (PREDL - 1)) * 2;
        float2 gt = *(const float2*)(traj_gt + og);
        *(float2*)(out + og) = make_float2(o0, o1);
        float d0 = o0 - gt.x, d1 = o1 - gt.y;
        lossAcc = fmaf(d0, d0, fmaf(d1, d1, lossAcc));
    }

    // ---- block loss partial (deterministic)
    #pragma unroll
    for (int s = 1; s < 64; s <<= 1) lossAcc += __shfl_xor(lossAcc, s, 64);
    float* sred = (float*)(smem + RED_OFF);
    if (lane == 0) sred[wave] = lossAcc;
    __syncthreads();
    if (tid == 0) {
        float s = 0.f;
        #pragma unroll
        for (int i = 0; i < 8; ++i) s += sred[i];
        wsloss[blockIdx.x] = s;
    }
}

__global__ void loss_reduce(const float* __restrict__ wsloss, float* __restrict__ out,
                            int npart, int nelem)
{
    __shared__ float sacc[4];
    int tid = threadIdx.x;   // 256
    float v = 0.f;
    for (int j = tid; j < npart; j += 256) v += wsloss[j];   // fixed order per lane
    #pragma unroll
    for (int s = 1; s < 64; s <<= 1) v += __shfl_xor(v, s, 64);
    if ((tid & 63) == 0) sacc[tid >> 6] = v;
    __syncthreads();
    if (tid == 0) out[nelem] = (sacc[0] + sacc[1] + sacc[2] + sacc[3]) / (float)nelem;
}

extern "C" void kernel_launch(void* const* d_in, const int* in_sizes, int n_in,
                              void* d_out, int out_size, void* d_ws, size_t ws_size,
                              hipStream_t stream)
{
    const float* traj_in = (const float*)d_in[0];
    const float* traj_gt = (const float*)d_in[1];
    const float* W_ih    = (const float*)d_in[2];
    const float* W_hh    = (const float*)d_in[3];
    const float* b_ih    = (const float*)d_in[4];
    const float* b_hh    = (const float*)d_in[5];
    const float* W_last  = (const float*)d_in[6];
    const float* b_last  = (const float*)d_in[7];
    float* out = (float*)d_out;
    float* wsloss = (float*)d_ws;

    const int B      = in_sizes[0] / (OBS * 2);   // 32768
    const int blocks = B / 64;                     // 512

    lstm_persist<<<blocks, 512, LDS_BYTES, stream>>>(traj_in, traj_gt, W_ih, W_hh,
                                                     b_ih, b_hh, W_last, b_last,
                                                     out, wsloss);
    loss_reduce<<<1, 256, 0, stream>>>(wsloss, out, blocks, out_size - 1);
}

// Round 13
// 181.135 us; speedup vs baseline: 2.8414x; 1.0417x over previous
//
#include <hip/hip_runtime.h>

#define OBS 8
#define PREDL 12
#define NCELL 19   // cell evals t=0..18; x_t=head(h_{t-1}) for t>=8; emit p=t-8; p=11 in tail

// LDS map (bytes) — exactly 160 KiB
#define W_OFF     0        // 98304: W_hh gates i,f,g (rows 0..383), 256B rows, swizzled(&15)
#define H_OFF     98304    // 2 x 16384: h double buffer, 64 rows x 256B, swizzled(&15)
#define RH_OFF    131072   // 2 x 16384: relu(h) double buffer, same layout
#define LDS_BYTES 163840

typedef short short8 __attribute__((ext_vector_type(8)));
typedef float f32x16 __attribute__((ext_vector_type(16)));
struct U128 { unsigned a, b, c, d; };

__device__ __forceinline__ float sigm(float x) {
    return __builtin_amdgcn_rcpf(1.0f + __builtin_amdgcn_exp2f(x * -1.4426950408889634f));
}
__device__ __forceinline__ float tanh_(float x) {
    return __builtin_amdgcn_rcpf(1.0f + __builtin_amdgcn_exp2f(x * -2.8853900817779268f)) * 2.0f - 1.0f;
}
__device__ __forceinline__ unsigned f2bf(float f) {
    unsigned u = __builtin_bit_cast(unsigned, f);
    u += 0x7fffu + ((u >> 16) & 1u);   // RNE
    return u >> 16;
}
__device__ __forceinline__ unsigned cvtpk(float lo, float hi) {
    unsigned r;
    asm("v_cvt_pk_bf16_f32 %0, %1, %2" : "=v"(r) : "v"(lo), "v"(hi));
    return r;
}

__global__ __attribute__((amdgpu_waves_per_eu(2, 2))) __launch_bounds__(512)
void lstm_persist(const float* __restrict__ traj_in, const float* __restrict__ traj_gt,
                  const float* __restrict__ W_ih, const float* __restrict__ W_hh,
                  const float* __restrict__ b_ih, const float* __restrict__ b_hh,
                  const float* __restrict__ W_last, const float* __restrict__ b_last,
                  float* __restrict__ out, float* __restrict__ wsloss)
{
    extern __shared__ char smem[];
    const int tid  = threadIdx.x;
    const int lane = tid & 63;
    const int wave = tid >> 6;          // 0..7
    const int l31  = lane & 31;
    const int half = lane >> 5;
    const int sw   = (l31 & 15) << 4;
    const int wm   = wave >> 2;         // rows wm*32..+31
    const int wc   = wave & 3;          // gate cols wc*32..+31
    const int col0 = wc * 32;
    const int rbase = blockIdx.x * 64;
    const int myrow = wm * 32 + l31;

    // ---- stage W_hh gates i,f,g (rows 0..383) -> LDS bf16, swizzled(&15)
    for (int it = 0; it < 24; ++it) {
        int i = it * 512 + tid;            // 12288 float4 items
        int n = i >> 5, c4 = i & 31;
        const float4 w = *(const float4*)(W_hh + (size_t)n * 128 + c4 * 4);
        uint2 pk = { f2bf(w.x) | (f2bf(w.y) << 16), f2bf(w.z) | (f2bf(w.w) << 16) };
        *(uint2*)(smem + W_OFF + n * 256 + ((c4 * 8) ^ ((n & 15) << 4))) = pk;
    }
    // ---- zero h buffer 0 only (buf1 / reluh fully written before first read)
    for (int i = 0; i < 8; ++i)
        *(unsigned*)(smem + H_OFF + (tid + i * 512) * 4) = 0u;

    // ---- ext B-fragments (x-weights + bias), 16 VGPRs
    short8 Ee[4];
    #pragma unroll
    for (int gg = 0; gg < 4; ++gg) {
        U128 v = { 0u, 0u, 0u, 0u };
        if (half == 0) {
            int n = gg * 128 + col0 + l31;
            float2 wi = *(const float2*)(W_ih + n * 2);
            float bsum = b_ih[n] + b_hh[n];
            v.a = f2bf(wi.x) | (f2bf(wi.y) << 16);
            v.b = f2bf(bsum);
        }
        Ee[gg] = __builtin_bit_cast(short8, v);
    }
    // ---- gate-o B-fragments -> 32 persistent VGPRs (loop-invariant)
    short8 Bo[8];
    #pragma unroll
    for (int ks = 0; ks < 8; ++ks) {
        const float* p = W_hh + (size_t)(384 + col0 + l31) * 128 + ks * 16 + half * 8;
        float4 u = *(const float4*)p;
        float4 v = *(const float4*)(p + 4);
        U128 q = { f2bf(u.x) | (f2bf(u.y) << 16), f2bf(u.z) | (f2bf(u.w) << 16),
                   f2bf(v.x) | (f2bf(v.y) << 16), f2bf(v.z) | (f2bf(v.w) << 16) };
        Bo[ks] = __builtin_bit_cast(short8, q);
    }
    // ---- W_last A-fragments (lanes 0,1 = output rows), 32 persistent VGPRs
    short8 Wl[8];
    #pragma unroll
    for (int ks = 0; ks < 8; ++ks) {
        U128 q = { 0u, 0u, 0u, 0u };
        if (l31 < 2) {
            const float* p = W_last + l31 * 128 + ks * 16 + half * 8;
            float4 u = *(const float4*)p;
            float4 v = *(const float4*)(p + 4);
            q.a = f2bf(u.x) | (f2bf(u.y) << 16); q.b = f2bf(u.z) | (f2bf(u.w) << 16);
            q.c = f2bf(v.x) | (f2bf(v.y) << 16); q.d = f2bf(v.z) | (f2bf(v.w) << 16);
        }
        Wl[ks] = __builtin_bit_cast(short8, q);
    }
    const float bl0 = b_last[0], bl1 = b_last[1];

    __syncthreads();

    float c_[16];
    #pragma unroll
    for (int r = 0; r < 16; ++r) c_[r] = 0.f;
    float lossAcc = 0.f;

    for (int t = 0; t < NCELL; ++t) {
        const int hcur  = H_OFF  + (t & 1) * 16384;
        const int hnxt  = H_OFF  + ((t & 1) ^ 1) * 16384;
        const int rhcur = RH_OFF + (t & 1) * 16384;
        const int rhnxt = RH_OFF + ((t & 1) ^ 1) * 16384;

        // ---- x for this step: obs from global; pred via per-wave head-MFMA
        float2 xx = make_float2(0.f, 0.f);
        if (t < OBS) {
            if (half == 0)
                xx = *(const float2*)(traj_in + ((size_t)(rbase + myrow) * OBS + t) * 2);
        } else {
            f32x16 hd{};
            #pragma unroll
            for (int ks = 0; ks < 8; ++ks) {
                short8 rb = *(const short8*)(smem + rhcur + myrow * 256 +
                                             ((ks * 32 + half * 16) ^ sw));
                hd = __builtin_amdgcn_mfma_f32_32x32x16_bf16(Wl[ks], rb, hd, 0, 0, 0);
            }
            if (half == 0) {
                xx.x = hd[0] + bl0;   // D[m=0][n=myrow] -> r=0, half=0
                xx.y = hd[1] + bl1;   // D[m=1][n=myrow] -> r=1, half=0
                if (wc == 0) {        // emit p = t-8
                    size_t og = ((size_t)(rbase + myrow) * PREDL + (t - OBS)) * 2;
                    float2 gt = *(const float2*)(traj_gt + og);
                    *(float2*)(out + og) = xx;
                    float d0 = xx.x - gt.x, d1 = xx.y - gt.y;
                    lossAcc = fmaf(d0, d0, fmaf(d1, d1, lossAcc));
                }
            }
        }

        // ---- A fragments from h[cur]
        short8 a[8];
        #pragma unroll
        for (int ks = 0; ks < 8; ++ks)
            a[ks] = *(const short8*)(smem + hcur + myrow * 256 + ((ks * 32 + half * 16) ^ sw));

        // ---- gates: K-ext (x,bias) + K=128 over i,f,g (LDS) and o (registers)
        unsigned xv = (half == 0) ? cvtpk(xx.x, xx.y) : 0u;
        U128 ax = { xv, (half == 0) ? 0x00003F80u : 0u, 0u, 0u };
        short8 aext = __builtin_bit_cast(short8, ax);

        f32x16 ac0{}, ac1{}, ac2{}, ac3{};
        ac0 = __builtin_amdgcn_mfma_f32_32x32x16_bf16(aext, Ee[0], ac0, 0, 0, 0);
        ac1 = __builtin_amdgcn_mfma_f32_32x32x16_bf16(aext, Ee[1], ac1, 0, 0, 0);
        ac2 = __builtin_amdgcn_mfma_f32_32x32x16_bf16(aext, Ee[2], ac2, 0, 0, 0);
        ac3 = __builtin_amdgcn_mfma_f32_32x32x16_bf16(aext, Ee[3], ac3, 0, 0, 0);
        #pragma unroll
        for (int ks = 0; ks < 8; ++ks) {
            const int bb = (ks * 32 + half * 16) ^ sw;
            const char* wb = smem + W_OFF + (col0 + l31) * 256 + bb;
            short8 bi  = *(const short8*)(wb);
            short8 bf_ = *(const short8*)(wb + 128 * 256);
            short8 bg  = *(const short8*)(wb + 256 * 256);
            ac0 = __builtin_amdgcn_mfma_f32_32x32x16_bf16(a[ks], bi,     ac0, 0, 0, 0);
            ac1 = __builtin_amdgcn_mfma_f32_32x32x16_bf16(a[ks], bf_,    ac1, 0, 0, 0);
            ac2 = __builtin_amdgcn_mfma_f32_32x32x16_bf16(a[ks], bg,     ac2, 0, 0, 0);
            ac3 = __builtin_amdgcn_mfma_f32_32x32x16_bf16(a[ks], Bo[ks], ac3, 0, 0, 0);
        }

        // ---- elementwise + packed h / relu(h) writes
        const bool doRelu = (t >= OBS - 1);
        #pragma unroll
        for (int r = 0; r < 16; ++r) {
            float iv = sigm(ac0[r]);
            float fv = sigm(ac1[r]);
            float gv = tanh_(ac2[r]);
            float ov = sigm(ac3[r]);
            float cv = fmaf(fv, c_[r], iv * gv);
            c_[r] = cv;
            float hv = ov * tanh_(cv);
            const int row  = (r & 3) + 8 * (r >> 2) + 4 * half;   // 0..31
            const int arow = wm * 32 + row;
            const int baddr = ((col0 + l31) * 2) ^ ((row & 15) << 4);
            float hn = __builtin_bit_cast(float,
                __builtin_amdgcn_update_dpp(0, __builtin_bit_cast(int, hv), 0xB1, 0xf, 0xf, true));
            unsigned hp = cvtpk(hv, hn);
            if (!(l31 & 1))
                *(unsigned*)(smem + hnxt + arow * 256 + baddr) = hp;
            if (doRelu) {
                unsigned rp = cvtpk(fmaxf(hv, 0.f), fmaxf(hn, 0.f));
                if (!(l31 & 1))
                    *(unsigned*)(smem + rhnxt + arow * 256 + baddr) = rp;
            }
        }
        __syncthreads();   // single barrier: h[nxt]/reluh[nxt] visible for t+1
    }

    // ---- tail: p = 11 = head(h_18); reluh parity buf[19&1 = 1]
    if (wc == 0) {
        f32x16 hd{};
        #pragma unroll
        for (int ks = 0; ks < 8; ++ks) {
            short8 rb = *(const short8*)(smem + RH_OFF + 16384 + myrow * 256 +
                                         ((ks * 32 + half * 16) ^ sw));
            hd = __builtin_amdgcn_mfma_f32_32x32x16_bf16(Wl[ks], rb, hd, 0, 0, 0);
        }
        if (half == 0) {
            float o0 = hd[0] + bl0, o1 = hd[1] + bl1;
            size_t og = ((size_t)(rbase + myrow) * PREDL + (PREDL - 1)) * 2;
            float2 gt = *(const float2*)(traj_gt + og);
            *(float2*)(out + og) = make_float2(o0, o1);
            float d0 = o0 - gt.x, d1 = o1 - gt.y;
            lossAcc = fmaf(d0, d0, fmaf(d1, d1, lossAcc));
        }
    }

    // ---- block loss partial (deterministic; reuse reluh buf0 as scratch)
    #pragma unroll
    for (int s = 1; s < 64; s <<= 1) lossAcc += __shfl_xor(lossAcc, s, 64);
    float* sred = (float*)(smem + RH_OFF);   // buf0: no longer read by anyone
    if (lane == 0) sred[wave] = lossAcc;
    __syncthreads();
    if (tid == 0) {
        float s = 0.f;
        #pragma unroll
        for (int i = 0; i < 8; ++i) s += sred[i];
        wsloss[blockIdx.x] = s;
    }
}

__global__ void loss_reduce(const float* __restrict__ wsloss, float* __restrict__ out,
                            int npart, int nelem)
{
    __shared__ float sacc[4];
    int tid = threadIdx.x;   // 256
    float v = 0.f;
    for (int j = tid; j < npart; j += 256) v += wsloss[j];   // fixed order per lane
    #pragma unroll
    for (int s = 1; s < 64; s <<= 1) v += __shfl_xor(v, s, 64);
    if ((tid & 63) == 0) sacc[tid >> 6] = v;
    __syncthreads();
    if (tid == 0) out[nelem] = (sacc[0] + sacc[1] + sacc[2] + sacc[3]) / (float)nelem;
}

extern "C" void kernel_launch(void* const* d_in, const int* in_sizes, int n_in,
                              void* d_out, int out_size, void* d_ws, size_t ws_size,
                              hipStream_t stream)
{
    const float* traj_in = (const float*)d_in[0];
    const float* traj_gt = (const float*)d_in[1];
    const float* W_ih    = (const float*)d_in[2];
    const float* W_hh    = (const float*)d_in[3];
    const float* b_ih    = (const float*)d_in[4];
    const float* b_hh    = (const float*)d_in[5];
    const float* W_last  = (const float*)d_in[6];
    const float* b_last  = (const float*)d_in[7];
    float* out = (float*)d_out;
    float* wsloss = (float*)d_ws;

    const int B      = in_sizes[0] / (OBS * 2);   // 32768
    const int blocks = B / 64;                     // 512

    lstm_persist<<<blocks, 512, LDS_BYTES, stream>>>(traj_in, traj_gt, W_ih, W_hh,
                                                     b_ih, b_hh, W_last, b_last,
                                                     out, wsloss);
    loss_reduce<<<1, 256, 0, stream>>>(wsloss, out, blocks, out_size - 1);
}

// Round 14
// 171.062 us; speedup vs baseline: 3.0087x; 1.0589x over previous
//
#include <hip/hip_runtime.h>

#define OBS 8
#define PREDL 12
#define NCELL 19   // cell evals t=0..18; x_t=head(h_{t-1}) for t>=8; emit p=t-8; p=11 in tail

// LDS map (bytes) — exactly 160 KiB
#define W_OFF     0        // 98304: W_hh gates i,f,g (rows 0..383), 256B rows, swizzled(&15)
#define H_OFF     98304    // 2 x 16384: h double buffer, 64 rows x 256B, swizzled(&15)
#define RH_OFF    131072   // 2 x 16384: relu(h) double buffer, same layout
#define LDS_BYTES 163840

typedef short short8 __attribute__((ext_vector_type(8)));
typedef float f32x16 __attribute__((ext_vector_type(16)));
struct U128 { unsigned a, b, c, d; };

__device__ __forceinline__ float sigm(float x) {
    return __builtin_amdgcn_rcpf(1.0f + __builtin_amdgcn_exp2f(x * -1.4426950408889634f));
}
__device__ __forceinline__ float tanh_(float x) {
    return __builtin_amdgcn_rcpf(1.0f + __builtin_amdgcn_exp2f(x * -2.8853900817779268f)) * 2.0f - 1.0f;
}
__device__ __forceinline__ unsigned f2bf(float f) {
    unsigned u = __builtin_bit_cast(unsigned, f);
    u += 0x7fffu + ((u >> 16) & 1u);   // RNE
    return u >> 16;
}
__device__ __forceinline__ unsigned cvtpk(float lo, float hi) {
    unsigned r;
    asm("v_cvt_pk_bf16_f32 %0, %1, %2" : "=v"(r) : "v"(lo), "v"(hi));
    return r;
}

__global__ __attribute__((amdgpu_waves_per_eu(2, 2))) __launch_bounds__(512)
void lstm_persist(const float* __restrict__ traj_in, const float* __restrict__ traj_gt,
                  const float* __restrict__ W_ih, const float* __restrict__ W_hh,
                  const float* __restrict__ b_ih, const float* __restrict__ b_hh,
                  const float* __restrict__ W_last, const float* __restrict__ b_last,
                  float* __restrict__ out, float* __restrict__ wsloss)
{
    extern __shared__ char smem[];
    const int tid  = threadIdx.x;
    const int lane = tid & 63;
    const int wave = tid >> 6;          // 0..7
    const int l31  = lane & 31;
    const int half = lane >> 5;
    const int sw   = (l31 & 15) << 4;
    const int wm   = wave >> 2;         // rows wm*32..+31
    const int wc   = wave & 3;          // gate cols wc*32..+31
    const int col0 = wc * 32;
    const int rbase = blockIdx.x * 64;
    const int myrow = wm * 32 + l31;

    // ---- stage W_hh gates i,f,g (rows 0..383) -> LDS bf16, swizzled(&15)
    for (int it = 0; it < 24; ++it) {
        int i = it * 512 + tid;            // 12288 float4 items
        int n = i >> 5, c4 = i & 31;
        const float4 w = *(const float4*)(W_hh + (size_t)n * 128 + c4 * 4);
        uint2 pk = { f2bf(w.x) | (f2bf(w.y) << 16), f2bf(w.z) | (f2bf(w.w) << 16) };
        *(uint2*)(smem + W_OFF + n * 256 + ((c4 * 8) ^ ((n & 15) << 4))) = pk;
    }
    // ---- zero h buffer 0 only (buf1 / reluh fully written before first read)
    for (int i = 0; i < 8; ++i)
        *(unsigned*)(smem + H_OFF + (tid + i * 512) * 4) = 0u;

    // ---- ext B-fragments (x-weights + bias), 16 VGPRs
    short8 Ee[4];
    #pragma unroll
    for (int gg = 0; gg < 4; ++gg) {
        U128 v = { 0u, 0u, 0u, 0u };
        if (half == 0) {
            int n = gg * 128 + col0 + l31;
            float2 wi = *(const float2*)(W_ih + n * 2);
            float bsum = b_ih[n] + b_hh[n];
            v.a = f2bf(wi.x) | (f2bf(wi.y) << 16);
            v.b = f2bf(bsum);
        }
        Ee[gg] = __builtin_bit_cast(short8, v);
    }
    // ---- gate-o B-fragments -> 32 persistent VGPRs (loop-invariant)
    short8 Bo[8];
    #pragma unroll
    for (int ks = 0; ks < 8; ++ks) {
        const float* p = W_hh + (size_t)(384 + col0 + l31) * 128 + ks * 16 + half * 8;
        float4 u = *(const float4*)p;
        float4 v = *(const float4*)(p + 4);
        U128 q = { f2bf(u.x) | (f2bf(u.y) << 16), f2bf(u.z) | (f2bf(u.w) << 16),
                   f2bf(v.x) | (f2bf(v.y) << 16), f2bf(v.z) | (f2bf(v.w) << 16) };
        Bo[ks] = __builtin_bit_cast(short8, q);
    }
    // ---- W_last A-fragments (lanes 0,1 = output rows), 32 persistent VGPRs
    short8 Wl[8];
    #pragma unroll
    for (int ks = 0; ks < 8; ++ks) {
        U128 q = { 0u, 0u, 0u, 0u };
        if (l31 < 2) {
            const float* p = W_last + l31 * 128 + ks * 16 + half * 8;
            float4 u = *(const float4*)p;
            float4 v = *(const float4*)(p + 4);
            q.a = f2bf(u.x) | (f2bf(u.y) << 16); q.b = f2bf(u.z) | (f2bf(u.w) << 16);
            q.c = f2bf(v.x) | (f2bf(v.y) << 16); q.d = f2bf(v.z) | (f2bf(v.w) << 16);
        }
        Wl[ks] = __builtin_bit_cast(short8, q);
    }
    const float bl0 = b_last[0], bl1 = b_last[1];

    __syncthreads();

    // persistent zero accumulator: used only as MFMA C-operand (never written again)
    f32x16 zacc{};

    float c_[16];
    #pragma unroll
    for (int r = 0; r < 16; ++r) c_[r] = 0.f;
    float lossAcc = 0.f;

    for (int t = 0; t < NCELL; ++t) {
        const int hcur  = H_OFF  + (t & 1) * 16384;
        const int hnxt  = H_OFF  + ((t & 1) ^ 1) * 16384;
        const int rhcur = RH_OFF + (t & 1) * 16384;
        const int rhnxt = RH_OFF + ((t & 1) ^ 1) * 16384;

        // ---- x for this step: obs from global; pred via per-wave head-MFMA
        float2 xx = make_float2(0.f, 0.f);
        if (t < OBS) {
            if (half == 0)
                xx = *(const float2*)(traj_in + ((size_t)(rbase + myrow) * OBS + t) * 2);
        } else {
            short8 rb0 = *(const short8*)(smem + rhcur + myrow * 256 + ((half * 16) ^ sw));
            f32x16 hd = __builtin_amdgcn_mfma_f32_32x32x16_bf16(Wl[0], rb0, zacc, 0, 0, 0);
            #pragma unroll
            for (int ks = 1; ks < 8; ++ks) {
                short8 rb = *(const short8*)(smem + rhcur + myrow * 256 +
                                             ((ks * 32 + half * 16) ^ sw));
                hd = __builtin_amdgcn_mfma_f32_32x32x16_bf16(Wl[ks], rb, hd, 0, 0, 0);
            }
            if (half == 0) {
                xx.x = hd[0] + bl0;   // D[m=0][n=myrow] -> r=0, half=0
                xx.y = hd[1] + bl1;   // D[m=1][n=myrow] -> r=1, half=0
                if (wc == 0) {        // emit p = t-8
                    size_t og = ((size_t)(rbase + myrow) * PREDL + (t - OBS)) * 2;
                    float2 gt = *(const float2*)(traj_gt + og);
                    *(float2*)(out + og) = xx;
                    float d0 = xx.x - gt.x, d1 = xx.y - gt.y;
                    lossAcc = fmaf(d0, d0, fmaf(d1, d1, lossAcc));
                }
            }
        }

        // ---- A fragments from h[cur]
        short8 a[8];
        #pragma unroll
        for (int ks = 0; ks < 8; ++ks)
            a[ks] = *(const short8*)(smem + hcur + myrow * 256 + ((ks * 32 + half * 16) ^ sw));

        // ---- gates: K-ext (x,bias) seeds acc via zacc; K=128 over i,f,g (LDS), o (regs)
        unsigned xv = (half == 0) ? cvtpk(xx.x, xx.y) : 0u;
        U128 ax = { xv, (half == 0) ? 0x00003F80u : 0u, 0u, 0u };
        short8 aext = __builtin_bit_cast(short8, ax);

        f32x16 ac0 = __builtin_amdgcn_mfma_f32_32x32x16_bf16(aext, Ee[0], zacc, 0, 0, 0);
        f32x16 ac1 = __builtin_amdgcn_mfma_f32_32x32x16_bf16(aext, Ee[1], zacc, 0, 0, 0);
        f32x16 ac2 = __builtin_amdgcn_mfma_f32_32x32x16_bf16(aext, Ee[2], zacc, 0, 0, 0);
        f32x16 ac3 = __builtin_amdgcn_mfma_f32_32x32x16_bf16(aext, Ee[3], zacc, 0, 0, 0);
        #pragma unroll
        for (int ks = 0; ks < 8; ++ks) {
            const int bb = (ks * 32 + half * 16) ^ sw;
            const char* wb = smem + W_OFF + (col0 + l31) * 256 + bb;
            short8 bi  = *(const short8*)(wb);
            short8 bf_ = *(const short8*)(wb + 128 * 256);
            short8 bg  = *(const short8*)(wb + 256 * 256);
            ac0 = __builtin_amdgcn_mfma_f32_32x32x16_bf16(a[ks], bi,     ac0, 0, 0, 0);
            ac1 = __builtin_amdgcn_mfma_f32_32x32x16_bf16(a[ks], bf_,    ac1, 0, 0, 0);
            ac2 = __builtin_amdgcn_mfma_f32_32x32x16_bf16(a[ks], bg,     ac2, 0, 0, 0);
            ac3 = __builtin_amdgcn_mfma_f32_32x32x16_bf16(a[ks], Bo[ks], ac3, 0, 0, 0);
        }

        // ---- elementwise + per-lane b16 h / relu(h) writes
        const bool doRelu = (t >= OBS - 1);
        #pragma unroll
        for (int r = 0; r < 16; ++r) {
            float iv = sigm(ac0[r]);
            float fv = sigm(ac1[r]);
            float gv = tanh_(ac2[r]);
            float ov = sigm(ac3[r]);
            float cv = fmaf(fv, c_[r], iv * gv);
            c_[r] = cv;
            float hv = ov * tanh_(cv);
            const int row  = (r & 3) + 8 * (r >> 2) + 4 * half;   // 0..31
            const int arow = wm * 32 + row;
            const int baddr = ((col0 + l31) * 2) ^ ((row & 15) << 4);
            float rl = fmaxf(hv, 0.f);
            unsigned hp = cvtpk(hv, rl);         // low = h, high = relu(h)
            *(short*)(smem + hnxt + arow * 256 + baddr) = (short)hp;
            if (doRelu)
                *(short*)(smem + rhnxt + arow * 256 + baddr) = (short)(hp >> 16);
        }
        __syncthreads();   // single barrier: h[nxt]/reluh[nxt] visible for t+1
    }

    // ---- tail: p = 11 = head(h_18); reluh parity buf[19&1 = 1]
    if (wc == 0) {
        short8 rb0 = *(const short8*)(smem + RH_OFF + 16384 + myrow * 256 + ((half * 16) ^ sw));
        f32x16 hd = __builtin_amdgcn_mfma_f32_32x32x16_bf16(Wl[0], rb0, zacc, 0, 0, 0);
        #pragma unroll
        for (int ks = 1; ks < 8; ++ks) {
            short8 rb = *(const short8*)(smem + RH_OFF + 16384 + myrow * 256 +
                                         ((ks * 32 + half * 16) ^ sw));
            hd = __builtin_amdgcn_mfma_f32_32x32x16_bf16(Wl[ks], rb, hd, 0, 0, 0);
        }
        if (half == 0) {
            float o0 = hd[0] + bl0, o1 = hd[1] + bl1;
            size_t og = ((size_t)(rbase + myrow) * PREDL + (PREDL - 1)) * 2;
            float2 gt = *(const float2*)(traj_gt + og);
            *(float2*)(out + og) = make_float2(o0, o1);
            float d0 = o0 - gt.x, d1 = o1 - gt.y;
            lossAcc = fmaf(d0, d0, fmaf(d1, d1, lossAcc));
        }
    }

    // ---- block loss partial (deterministic; reuse reluh buf0 as scratch)
    #pragma unroll
    for (int s = 1; s < 64; s <<= 1) lossAcc += __shfl_xor(lossAcc, s, 64);
    float* sred = (float*)(smem + RH_OFF);   // buf0: no longer read by anyone
    if (lane == 0) sred[wave] = lossAcc;
    __syncthreads();
    if (tid == 0) {
        float s = 0.f;
        #pragma unroll
        for (int i = 0; i < 8; ++i) s += sred[i];
        wsloss[blockIdx.x] = s;
    }
}

__global__ void loss_reduce(const float* __restrict__ wsloss, float* __restrict__ out,
                            int npart, int nelem)
{
    __shared__ float sacc[4];
    int tid = threadIdx.x;   // 256
    float v = 0.f;
    for (int j = tid; j < npart; j += 256) v += wsloss[j];   // fixed order per lane
    #pragma unroll
    for (int s = 1; s < 64; s <<= 1) v += __shfl_xor(v, s, 64);
    if ((tid & 63) == 0) sacc[tid >> 6] = v;
    __syncthreads();
    if (tid == 0) out[nelem] = (sacc[0] + sacc[1] + sacc[2] + sacc[3]) / (float)nelem;
}

extern "C" void kernel_launch(void* const* d_in, const int* in_sizes, int n_in,
                              void* d_out, int out_size, void* d_ws, size_t ws_size,
                              hipStream_t stream)
{
    const float* traj_in = (const float*)d_in[0];
    const float* traj_gt = (const float*)d_in[1];
    const float* W_ih    = (const float*)d_in[2];
    const float* W_hh    = (const float*)d_in[3];
    const float* b_ih    = (const float*)d_in[4];
    const float* b_hh    = (const float*)d_in[5];
    const float* W_last  = (const float*)d_in[6];
    const float* b_last  = (const float*)d_in[7];
    float* out = (float*)d_out;
    float* wsloss = (float*)d_ws;

    const int B      = in_sizes[0] / (OBS * 2);   // 32768
    const int blocks = B / 64;                     // 512

    lstm_persist<<<blocks, 512, LDS_BYTES, stream>>>(traj_in, traj_gt, W_ih, W_hh,
                                                     b_ih, b_hh, W_last, b_last,
                                                     out, wsloss);
    loss_reduce<<<1, 256, 0, stream>>>(wsloss, out, blocks, out_size - 1);
}

// Round 15
// 154.049 us; speedup vs baseline: 3.3410x; 1.1104x over previous
//
#include <hip/hip_runtime.h>

#define OBS 8
#define PREDL 12
#define NCELL 19   // cell evals t=0..18; x_t=head(h_{t-1}) for t>=8; emit p=t-8; p=11 in tail

// LDS map (bytes) — exactly 160 KiB
#define W_OFF     0        // 98304: W_hh gates i,f,g (rows 0..383), 256B rows, swizzled(&15)
#define H_OFF     98304    // 2 x 16384: h double buffer, 64 rows x 256B, swizzled(&15)
#define RH_OFF    131072   // 2 x 16384: relu(h) double buffer, same layout
#define LDS_BYTES 163840

typedef short short8 __attribute__((ext_vector_type(8)));
typedef float f32x16 __attribute__((ext_vector_type(16)));
struct U128 { unsigned a, b, c, d; };

__device__ __forceinline__ float sigm(float x) {
    return __builtin_amdgcn_rcpf(1.0f + __builtin_amdgcn_exp2f(x * -1.4426950408889634f));
}
__device__ __forceinline__ float tanh_(float x) {
    return __builtin_amdgcn_rcpf(1.0f + __builtin_amdgcn_exp2f(x * -2.8853900817779268f)) * 2.0f - 1.0f;
}
__device__ __forceinline__ unsigned f2bf(float f) {
    unsigned u = __builtin_bit_cast(unsigned, f);
    u += 0x7fffu + ((u >> 16) & 1u);   // RNE
    return u >> 16;
}
__device__ __forceinline__ unsigned cvtpk(float lo, float hi) {
    unsigned r;
    asm("v_cvt_pk_bf16_f32 %0, %1, %2" : "=v"(r) : "v"(lo), "v"(hi));
    return r;
}

__global__ __attribute__((amdgpu_waves_per_eu(2, 2))) __launch_bounds__(512)
void lstm_persist(const float* __restrict__ traj_in, const float* __restrict__ traj_gt,
                  const float* __restrict__ W_ih, const float* __restrict__ W_hh,
                  const float* __restrict__ b_ih, const float* __restrict__ b_hh,
                  const float* __restrict__ W_last, const float* __restrict__ b_last,
                  float* __restrict__ out, float* __restrict__ wsloss)
{
    extern __shared__ char smem[];
    const int tid  = threadIdx.x;
    const int lane = tid & 63;
    const int wave = tid >> 6;          // 0..7
    const int l31  = lane & 31;
    const int half = lane >> 5;
    const int sw   = (l31 & 15) << 4;
    const int wm   = wave >> 2;         // rows wm*32..+31
    const int wc   = wave & 3;          // gate cols wc*32..+31
    const int col0 = wc * 32;
    const int myrow = wm * 32 + l31;

    // ---- stage W_hh gates i,f,g (rows 0..383) -> LDS bf16, swizzled(&15), ONCE
    for (int it = 0; it < 24; ++it) {
        int i = it * 512 + tid;            // 12288 float4 items
        int n = i >> 5, c4 = i & 31;
        const float4 w = *(const float4*)(W_hh + (size_t)n * 128 + c4 * 4);
        uint2 pk = { f2bf(w.x) | (f2bf(w.y) << 16), f2bf(w.z) | (f2bf(w.w) << 16) };
        *(uint2*)(smem + W_OFF + n * 256 + ((c4 * 8) ^ ((n & 15) << 4))) = pk;
    }

    // ---- ext B-fragments (x-weights + bias), 16 VGPRs
    short8 Ee[4];
    #pragma unroll
    for (int gg = 0; gg < 4; ++gg) {
        U128 v = { 0u, 0u, 0u, 0u };
        if (half == 0) {
            int n = gg * 128 + col0 + l31;
            float2 wi = *(const float2*)(W_ih + n * 2);
            float bsum = b_ih[n] + b_hh[n];
            v.a = f2bf(wi.x) | (f2bf(wi.y) << 16);
            v.b = f2bf(bsum);
        }
        Ee[gg] = __builtin_bit_cast(short8, v);
    }
    // ---- gate-o B-fragments -> 32 persistent VGPRs (loop-invariant)
    short8 Bo[8];
    #pragma unroll
    for (int ks = 0; ks < 8; ++ks) {
        const float* p = W_hh + (size_t)(384 + col0 + l31) * 128 + ks * 16 + half * 8;
        float4 u = *(const float4*)p;
        float4 v = *(const float4*)(p + 4);
        U128 q = { f2bf(u.x) | (f2bf(u.y) << 16), f2bf(u.z) | (f2bf(u.w) << 16),
                   f2bf(v.x) | (f2bf(v.y) << 16), f2bf(v.z) | (f2bf(v.w) << 16) };
        Bo[ks] = __builtin_bit_cast(short8, q);
    }
    // ---- W_last A-fragments (lanes 0,1 = output rows), 32 persistent VGPRs
    short8 Wl[8];
    #pragma unroll
    for (int ks = 0; ks < 8; ++ks) {
        U128 q = { 0u, 0u, 0u, 0u };
        if (l31 < 2) {
            const float* p = W_last + l31 * 128 + ks * 16 + half * 8;
            float4 u = *(const float4*)p;
            float4 v = *(const float4*)(p + 4);
            q.a = f2bf(u.x) | (f2bf(u.y) << 16); q.b = f2bf(u.z) | (f2bf(u.w) << 16);
            q.c = f2bf(v.x) | (f2bf(v.y) << 16); q.d = f2bf(v.z) | (f2bf(v.w) << 16);
        }
        Wl[ks] = __builtin_bit_cast(short8, q);
    }
    const float bl0 = b_last[0], bl1 = b_last[1];

    // persistent zero accumulator: used only as MFMA C-operand
    f32x16 zacc{};
    float lossAcc = 0.f;

    for (int g = 0; g < 2; ++g) {
        const int rbase = blockIdx.x * 128 + g * 64;

        // ---- zero h buffer 0 (buf1/reluh fully written before first read)
        for (int i = 0; i < 8; ++i)
            *(unsigned*)(smem + H_OFF + (tid + i * 512) * 4) = 0u;
        __syncthreads();

        float c_[16];
        #pragma unroll
        for (int r = 0; r < 16; ++r) c_[r] = 0.f;

        for (int t = 0; t < NCELL; ++t) {
            const int hcur  = H_OFF  + (t & 1) * 16384;
            const int hnxt  = H_OFF  + ((t & 1) ^ 1) * 16384;
            const int rhcur = RH_OFF + (t & 1) * 16384;
            const int rhnxt = RH_OFF + ((t & 1) ^ 1) * 16384;

            // ---- x for this step (runs concurrent with main MFMAs; consumed at end)
            float2 xx = make_float2(0.f, 0.f);
            if (t < OBS) {
                if (half == 0)
                    xx = *(const float2*)(traj_in + ((size_t)(rbase + myrow) * OBS + t) * 2);
            } else {
                short8 rb0 = *(const short8*)(smem + rhcur + myrow * 256 + ((half * 16) ^ sw));
                f32x16 hd = __builtin_amdgcn_mfma_f32_32x32x16_bf16(Wl[0], rb0, zacc, 0, 0, 0);
                #pragma unroll
                for (int ks = 1; ks < 8; ++ks) {
                    short8 rb = *(const short8*)(smem + rhcur + myrow * 256 +
                                                 ((ks * 32 + half * 16) ^ sw));
                    hd = __builtin_amdgcn_mfma_f32_32x32x16_bf16(Wl[ks], rb, hd, 0, 0, 0);
                }
                if (half == 0) {
                    xx.x = hd[0] + bl0;   // D[m=0][n=myrow] -> r=0, half=0
                    xx.y = hd[1] + bl1;   // D[m=1][n=myrow] -> r=1, half=0
                    if (wc == 0) {        // emit p = t-8
                        size_t og = ((size_t)(rbase + myrow) * PREDL + (t - OBS)) * 2;
                        float2 gt = *(const float2*)(traj_gt + og);
                        *(float2*)(out + og) = xx;
                        float d0 = xx.x - gt.x, d1 = xx.y - gt.y;
                        lossAcc = fmaf(d0, d0, fmaf(d1, d1, lossAcc));
                    }
                }
            }

            // ---- A fragments from h[cur]
            short8 a[8];
            #pragma unroll
            for (int ks = 0; ks < 8; ++ks)
                a[ks] = *(const short8*)(smem + hcur + myrow * 256 + ((ks * 32 + half * 16) ^ sw));

            // ---- main K=128 first (seeded by zacc), ext (x,bias) appended LAST
            f32x16 ac0, ac1, ac2, ac3;
            {
                const int bb = (half * 16) ^ sw;
                const char* wb = smem + W_OFF + (col0 + l31) * 256 + bb;
                ac0 = __builtin_amdgcn_mfma_f32_32x32x16_bf16(a[0], *(const short8*)(wb),             zacc, 0, 0, 0);
                ac1 = __builtin_amdgcn_mfma_f32_32x32x16_bf16(a[0], *(const short8*)(wb + 128 * 256), zacc, 0, 0, 0);
                ac2 = __builtin_amdgcn_mfma_f32_32x32x16_bf16(a[0], *(const short8*)(wb + 256 * 256), zacc, 0, 0, 0);
                ac3 = __builtin_amdgcn_mfma_f32_32x32x16_bf16(a[0], Bo[0],                            zacc, 0, 0, 0);
            }
            #pragma unroll
            for (int ks = 1; ks < 8; ++ks) {
                const int bb = (ks * 32 + half * 16) ^ sw;
                const char* wb = smem + W_OFF + (col0 + l31) * 256 + bb;
                short8 bi  = *(const short8*)(wb);
                short8 bf_ = *(const short8*)(wb + 128 * 256);
                short8 bg  = *(const short8*)(wb + 256 * 256);
                ac0 = __builtin_amdgcn_mfma_f32_32x32x16_bf16(a[ks], bi,     ac0, 0, 0, 0);
                ac1 = __builtin_amdgcn_mfma_f32_32x32x16_bf16(a[ks], bf_,    ac1, 0, 0, 0);
                ac2 = __builtin_amdgcn_mfma_f32_32x32x16_bf16(a[ks], bg,     ac2, 0, 0, 0);
                ac3 = __builtin_amdgcn_mfma_f32_32x32x16_bf16(a[ks], Bo[ks], ac3, 0, 0, 0);
            }
            {   // K-extension slice last: x * W_ih^T + bias
                unsigned xv = (half == 0) ? cvtpk(xx.x, xx.y) : 0u;
                U128 ax = { xv, (half == 0) ? 0x00003F80u : 0u, 0u, 0u };
                short8 aext = __builtin_bit_cast(short8, ax);
                ac0 = __builtin_amdgcn_mfma_f32_32x32x16_bf16(aext, Ee[0], ac0, 0, 0, 0);
                ac1 = __builtin_amdgcn_mfma_f32_32x32x16_bf16(aext, Ee[1], ac1, 0, 0, 0);
                ac2 = __builtin_amdgcn_mfma_f32_32x32x16_bf16(aext, Ee[2], ac2, 0, 0, 0);
                ac3 = __builtin_amdgcn_mfma_f32_32x32x16_bf16(aext, Ee[3], ac3, 0, 0, 0);
            }

            // ---- elementwise + per-lane b16 h / relu(h) writes
            const bool doRelu = (t >= OBS - 1);
            #pragma unroll
            for (int r = 0; r < 16; ++r) {
                float iv = sigm(ac0[r]);
                float fv = sigm(ac1[r]);
                float gv = tanh_(ac2[r]);
                float ov = sigm(ac3[r]);
                float cv = fmaf(fv, c_[r], iv * gv);
                c_[r] = cv;
                float hv = ov * tanh_(cv);
                const int row  = (r & 3) + 8 * (r >> 2) + 4 * half;   // 0..31
                const int arow = wm * 32 + row;
                const int baddr = ((col0 + l31) * 2) ^ ((row & 15) << 4);
                float rl = fmaxf(hv, 0.f);
                unsigned hp = cvtpk(hv, rl);         // low = h, high = relu(h)
                *(short*)(smem + hnxt + arow * 256 + baddr) = (short)hp;
                if (doRelu)
                    *(short*)(smem + rhnxt + arow * 256 + baddr) = (short)(hp >> 16);
            }
            __syncthreads();   // single barrier: h[nxt]/reluh[nxt] visible for t+1
        }

        // ---- tail: p = 11 = head(h_18); reluh parity buf[19&1 = 1]
        if (wc == 0) {
            short8 rb0 = *(const short8*)(smem + RH_OFF + 16384 + myrow * 256 + ((half * 16) ^ sw));
            f32x16 hd = __builtin_amdgcn_mfma_f32_32x32x16_bf16(Wl[0], rb0, zacc, 0, 0, 0);
            #pragma unroll
            for (int ks = 1; ks < 8; ++ks) {
                short8 rb = *(const short8*)(smem + RH_OFF + 16384 + myrow * 256 +
                                             ((ks * 32 + half * 16) ^ sw));
                hd = __builtin_amdgcn_mfma_f32_32x32x16_bf16(Wl[ks], rb, hd, 0, 0, 0);
            }
            if (half == 0) {
                float o0 = hd[0] + bl0, o1 = hd[1] + bl1;
                size_t og = ((size_t)(rbase + myrow) * PREDL + (PREDL - 1)) * 2;
                float2 gt = *(const float2*)(traj_gt + og);
                *(float2*)(out + og) = make_float2(o0, o1);
                float d0 = o0 - gt.x, d1 = o1 - gt.y;
                lossAcc = fmaf(d0, d0, fmaf(d1, d1, lossAcc));
            }
        }
        __syncthreads();   // group done before h re-zero / next-group writes
    }

    // ---- block loss partial (deterministic; reuse reluh buf0 as scratch)
    #pragma unroll
    for (int s = 1; s < 64; s <<= 1) lossAcc += __shfl_xor(lossAcc, s, 64);
    float* sred = (float*)(smem + RH_OFF);   // buf0: no longer read
    if (lane == 0) sred[wave] = lossAcc;
    __syncthreads();
    if (tid == 0) {
        float s = 0.f;
        #pragma unroll
        for (int i = 0; i < 8; ++i) s += sred[i];
        wsloss[blockIdx.x] = s;
    }
}

__global__ void loss_reduce(const float* __restrict__ wsloss, float* __restrict__ out,
                            int npart, int nelem)
{
    __shared__ float sacc[4];
    int tid = threadIdx.x;   // 256
    float v = 0.f;
    for (int j = tid; j < npart; j += 256) v += wsloss[j];   // fixed order per lane
    #pragma unroll
    for (int s = 1; s < 64; s <<= 1) v += __shfl_xor(v, s, 64);
    if ((tid & 63) == 0) sacc[tid >> 6] = v;
    __syncthreads();
    if (tid == 0) out[nelem] = (sacc[0] + sacc[1] + sacc[2] + sacc[3]) / (float)nelem;
}

extern "C" void kernel_launch(void* const* d_in, const int* in_sizes, int n_in,
                              void* d_out, int out_size, void* d_ws, size_t ws_size,
                              hipStream_t stream)
{
    const float* traj_in = (const float*)d_in[0];
    const float* traj_gt = (const float*)d_in[1];
    const float* W_ih    = (const float*)d_in[2];
    const float* W_hh    = (const float*)d_in[3];
    const float* b_ih    = (const float*)d_in[4];
    const float* b_hh    = (const float*)d_in[5];
    const float* W_last  = (const float*)d_in[6];
    const float* b_last  = (const float*)d_in[7];
    float* out = (float*)d_out;
    float* wsloss = (float*)d_ws;

    const int B      = in_sizes[0] / (OBS * 2);   // 32768
    const int blocks = B / 128;                    // 256 (2 groups of 64 rows per block)

    lstm_persist<<<blocks, 512, LDS_BYTES, stream>>>(traj_in, traj_gt, W_ih, W_hh,
                                                     b_ih, b_hh, W_last, b_last,
                                                     out, wsloss);
    loss_reduce<<<1, 256, 0, stream>>>(wsloss, out, blocks, out_size - 1);
}

// Round 16
// 146.790 us; speedup vs baseline: 3.5062x; 1.0494x over previous
//
#include <hip/hip_runtime.h>

#define OBS 8
#define PREDL 12
#define NCELL 19   // cell evals t=0..18; x_t=head(h_{t-1}) for t>=8; emit p=t-8; p=11 in tail

// LDS map (bytes) — exactly 160 KiB
#define W_OFF     0        // 98304: W_hh gates i,f,g interleaved: (col*3+gate)*256, swizzled(&15)
#define H_OFF     98304    // 2 x 16384: h double buffer, 64 rows x 256B, swizzled(&15)
#define RH_OFF    131072   // 2 x 16384: relu(h) double buffer, same layout
#define LDS_BYTES 163840

typedef short short8 __attribute__((ext_vector_type(8)));
typedef float f32x16 __attribute__((ext_vector_type(16)));
struct U128 { unsigned a, b, c, d; };

#define NL2E  (-1.4426950408889634f)   // -log2(e)
#define N2L2E (-2.8853900817779268f)   // -2*log2(e)

__device__ __forceinline__ float sigm_p(float y) {   // y pre-scaled: sigm = rcp(1+2^y)
    return __builtin_amdgcn_rcpf(1.0f + __builtin_amdgcn_exp2f(y));
}
__device__ __forceinline__ unsigned f2bf(float f) {
    unsigned u = __builtin_bit_cast(unsigned, f);
    u += 0x7fffu + ((u >> 16) & 1u);   // RNE
    return u >> 16;
}
__device__ __forceinline__ unsigned cvtpk(float lo, float hi) {
    unsigned r;
    asm("v_cvt_pk_bf16_f32 %0, %1, %2" : "=v"(r) : "v"(lo), "v"(hi));
    return r;
}

__global__ __attribute__((amdgpu_waves_per_eu(2, 2))) __launch_bounds__(512)
void lstm_persist(const float* __restrict__ traj_in, const float* __restrict__ traj_gt,
                  const float* __restrict__ W_ih, const float* __restrict__ W_hh,
                  const float* __restrict__ b_ih, const float* __restrict__ b_hh,
                  const float* __restrict__ W_last, const float* __restrict__ b_last,
                  float* __restrict__ out, float* __restrict__ wsloss)
{
    extern __shared__ char smem[];
    const int tid  = threadIdx.x;
    const int lane = tid & 63;
    const int wave = tid >> 6;          // 0..7
    const int l31  = lane & 31;
    const int half = lane >> 5;
    const int sw   = (l31 & 15) << 4;
    const int wm   = wave >> 2;         // rows wm*32..+31
    const int wc   = wave & 3;          // gate cols wc*32..+31
    const int col0 = wc * 32;
    const int myrow = wm * 32 + l31;

    // ---- stage W_hh gates i,f,g -> LDS bf16, interleaved (col*3+gate)*256, PRESCALED
    for (int it = 0; it < 24; ++it) {
        int i = it * 512 + tid;            // 12288 float4 items, rows 0..383
        int n = i >> 5, c4 = i & 31;
        int gi = n >> 7, cn = n & 127;
        float sc = (gi == 2) ? N2L2E : NL2E;
        const float4 w = *(const float4*)(W_hh + (size_t)n * 128 + c4 * 4);
        uint2 pk = { f2bf(w.x * sc) | (f2bf(w.y * sc) << 16),
                     f2bf(w.z * sc) | (f2bf(w.w * sc) << 16) };
        *(uint2*)(smem + W_OFF + (cn * 3 + gi) * 256 + ((c4 * 8) ^ ((cn & 15) << 4))) = pk;
    }

    // ---- ext B-fragments (x-weights + bias), PRESCALED, 16 VGPRs
    short8 Ee[4];
    #pragma unroll
    for (int gg = 0; gg < 4; ++gg) {
        U128 v = { 0u, 0u, 0u, 0u };
        if (half == 0) {
            int n = gg * 128 + col0 + l31;
            float sc = (gg == 2) ? N2L2E : NL2E;
            float2 wi = *(const float2*)(W_ih + n * 2);
            float bsum = (b_ih[n] + b_hh[n]) * sc;
            v.a = f2bf(wi.x * sc) | (f2bf(wi.y * sc) << 16);
            v.b = f2bf(bsum);
        }
        Ee[gg] = __builtin_bit_cast(short8, v);
    }
    // ---- gate-o B-fragments -> 32 persistent VGPRs, PRESCALED
    short8 Bo[8];
    #pragma unroll
    for (int ks = 0; ks < 8; ++ks) {
        const float* p = W_hh + (size_t)(384 + col0 + l31) * 128 + ks * 16 + half * 8;
        float4 u = *(const float4*)p;
        float4 v = *(const float4*)(p + 4);
        U128 q = { f2bf(u.x * NL2E) | (f2bf(u.y * NL2E) << 16),
                   f2bf(u.z * NL2E) | (f2bf(u.w * NL2E) << 16),
                   f2bf(v.x * NL2E) | (f2bf(v.y * NL2E) << 16),
                   f2bf(v.z * NL2E) | (f2bf(v.w * NL2E) << 16) };
        Bo[ks] = __builtin_bit_cast(short8, q);
    }
    // ---- W_last A-fragments (lanes 0,1 = output rows), UNSCALED, 32 VGPRs
    short8 Wl[8];
    #pragma unroll
    for (int ks = 0; ks < 8; ++ks) {
        U128 q = { 0u, 0u, 0u, 0u };
        if (l31 < 2) {
            const float* p = W_last + l31 * 128 + ks * 16 + half * 8;
            float4 u = *(const float4*)p;
            float4 v = *(const float4*)(p + 4);
            q.a = f2bf(u.x) | (f2bf(u.y) << 16); q.b = f2bf(u.z) | (f2bf(u.w) << 16);
            q.c = f2bf(v.x) | (f2bf(v.y) << 16); q.d = f2bf(v.z) | (f2bf(v.w) << 16);
        }
        Wl[ks] = __builtin_bit_cast(short8, q);
    }
    const float bl0 = b_last[0], bl1 = b_last[1];

    // ---- precomputed step-invariant LDS addresses (kept in registers)
    int aAddr[8], wAddr[8], hAddr[16];
    #pragma unroll
    for (int ks = 0; ks < 8; ++ks) {
        const int bv = (ks * 32 + half * 16) ^ sw;
        aAddr[ks] = H_OFF + myrow * 256 + bv;
        wAddr[ks] = W_OFF + (col0 + l31) * 768 + bv;
    }
    #pragma unroll
    for (int r = 0; r < 16; ++r) {
        const int row = (r & 3) + 8 * (r >> 2) + 4 * half;   // 0..31
        hAddr[r] = H_OFF + (wm * 32 + row) * 256 + (((col0 + l31) * 2) ^ ((row & 15) << 4));
    }

    // persistent zero accumulator: used only as MFMA C-operand
    f32x16 zacc{};
    float lossAcc = 0.f;

    for (int g = 0; g < 2; ++g) {
        const int rbase = blockIdx.x * 128 + g * 64;

        // ---- zero h buffer 0 (buf1/reluh fully written before first read)
        for (int i = 0; i < 8; ++i)
            *(unsigned*)(smem + H_OFF + (tid + i * 512) * 4) = 0u;
        __syncthreads();

        float c_[16];
        #pragma unroll
        for (int r = 0; r < 16; ++r) c_[r] = 0.f;

        for (int t = 0; t < NCELL; ++t) {
            const int hparR = (t & 1) * 16384;      // current h/rh parity offset
            const int hparW = 16384 - hparR;        // next-buffer parity offset

            // ---- x for this step (concurrent with main MFMAs; consumed at end)
            float2 xx = make_float2(0.f, 0.f);
            if (t < OBS) {
                if (half == 0)
                    xx = *(const float2*)(traj_in + ((size_t)(rbase + myrow) * OBS + t) * 2);
            } else {
                short8 rb0 = *(const short8*)(smem + aAddr[0] + 32768 + hparR);
                f32x16 hd = __builtin_amdgcn_mfma_f32_32x32x16_bf16(Wl[0], rb0, zacc, 0, 0, 0);
                #pragma unroll
                for (int ks = 1; ks < 8; ++ks) {
                    short8 rb = *(const short8*)(smem + aAddr[ks] + 32768 + hparR);
                    hd = __builtin_amdgcn_mfma_f32_32x32x16_bf16(Wl[ks], rb, hd, 0, 0, 0);
                }
                if (half == 0) {
                    xx.x = hd[0] + bl0;   // D[m=0][n=myrow] -> r=0, half=0
                    xx.y = hd[1] + bl1;
                    if (wc == 0) {        // emit p = t-8
                        size_t og = ((size_t)(rbase + myrow) * PREDL + (t - OBS)) * 2;
                        float2 gt = *(const float2*)(traj_gt + og);
                        *(float2*)(out + og) = xx;
                        float d0 = xx.x - gt.x, d1 = xx.y - gt.y;
                        lossAcc = fmaf(d0, d0, fmaf(d1, d1, lossAcc));
                    }
                }
            }

            // ---- A fragments from h[cur]
            short8 a[8];
            #pragma unroll
            for (int ks = 0; ks < 8; ++ks)
                a[ks] = *(const short8*)(smem + aAddr[ks] + hparR);

            // ---- main K=128 first (seeded by zacc), ext (x,bias) appended LAST
            f32x16 ac0, ac1, ac2, ac3;
            {
                const char* wb = smem + wAddr[0];
                ac0 = __builtin_amdgcn_mfma_f32_32x32x16_bf16(a[0], *(const short8*)(wb),       zacc, 0, 0, 0);
                ac1 = __builtin_amdgcn_mfma_f32_32x32x16_bf16(a[0], *(const short8*)(wb + 256), zacc, 0, 0, 0);
                ac2 = __builtin_amdgcn_mfma_f32_32x32x16_bf16(a[0], *(const short8*)(wb + 512), zacc, 0, 0, 0);
                ac3 = __builtin_amdgcn_mfma_f32_32x32x16_bf16(a[0], Bo[0],                      zacc, 0, 0, 0);
            }
            #pragma unroll
            for (int ks = 1; ks < 8; ++ks) {
                const char* wb = smem + wAddr[ks];
                short8 bi  = *(const short8*)(wb);
                short8 bf_ = *(const short8*)(wb + 256);
                short8 bg  = *(const short8*)(wb + 512);
                ac0 = __builtin_amdgcn_mfma_f32_32x32x16_bf16(a[ks], bi,     ac0, 0, 0, 0);
                ac1 = __builtin_amdgcn_mfma_f32_32x32x16_bf16(a[ks], bf_,    ac1, 0, 0, 0);
                ac2 = __builtin_amdgcn_mfma_f32_32x32x16_bf16(a[ks], bg,     ac2, 0, 0, 0);
                ac3 = __builtin_amdgcn_mfma_f32_32x32x16_bf16(a[ks], Bo[ks], ac3, 0, 0, 0);
            }
            {   // K-extension slice last: x * W_ih^T + bias (prescaled)
                unsigned xv = (half == 0) ? cvtpk(xx.x, xx.y) : 0u;
                U128 ax = { xv, (half == 0) ? 0x00003F80u : 0u, 0u, 0u };
                short8 aext = __builtin_bit_cast(short8, ax);
                ac0 = __builtin_amdgcn_mfma_f32_32x32x16_bf16(aext, Ee[0], ac0, 0, 0, 0);
                ac1 = __builtin_amdgcn_mfma_f32_32x32x16_bf16(aext, Ee[1], ac1, 0, 0, 0);
                ac2 = __builtin_amdgcn_mfma_f32_32x32x16_bf16(aext, Ee[2], ac2, 0, 0, 0);
                ac3 = __builtin_amdgcn_mfma_f32_32x32x16_bf16(aext, Ee[3], ac3, 0, 0, 0);
            }

            // ---- elementwise (exp2-ready args) + per-lane b16 h / relu(h) writes
            const bool doRelu = (t >= OBS - 1);
            #pragma unroll
            for (int r = 0; r < 16; ++r) {
                float iv = sigm_p(ac0[r]);
                float fv = sigm_p(ac1[r]);
                float gv = fmaf(2.f, sigm_p(ac2[r]), -1.f);
                float ov = sigm_p(ac3[r]);
                float cv = fmaf(fv, c_[r], iv * gv);
                c_[r] = cv;
                float th = fmaf(2.f, sigm_p(cv * N2L2E), -1.f);
                float hv = ov * th;
                float rl = fmaxf(hv, 0.f);
                unsigned hp = cvtpk(hv, rl);         // low = h, high = relu(h)
                *(short*)(smem + hAddr[r] + hparW) = (short)hp;
                if (doRelu)
                    *(short*)(smem + hAddr[r] + hparW + 32768) = (short)(hp >> 16);
            }
            __syncthreads();   // single barrier: h[nxt]/reluh[nxt] visible for t+1
        }

        // ---- tail: p = 11 = head(h_18); reluh parity buf 1 -> aAddr + 49152
        if (wc == 0) {
            short8 rb0 = *(const short8*)(smem + aAddr[0] + 49152);
            f32x16 hd = __builtin_amdgcn_mfma_f32_32x32x16_bf16(Wl[0], rb0, zacc, 0, 0, 0);
            #pragma unroll
            for (int ks = 1; ks < 8; ++ks) {
                short8 rb = *(const short8*)(smem + aAddr[ks] + 49152);
                hd = __builtin_amdgcn_mfma_f32_32x32x16_bf16(Wl[ks], rb, hd, 0, 0, 0);
            }
            if (half == 0) {
                float o0 = hd[0] + bl0, o1 = hd[1] + bl1;
                size_t og = ((size_t)(rbase + myrow) * PREDL + (PREDL - 1)) * 2;
                float2 gt = *(const float2*)(traj_gt + og);
                *(float2*)(out + og) = make_float2(o0, o1);
                float d0 = o0 - gt.x, d1 = o1 - gt.y;
                lossAcc = fmaf(d0, d0, fmaf(d1, d1, lossAcc));
            }
        }
        __syncthreads();   // group done before h re-zero / next-group writes
    }

    // ---- block loss partial (deterministic; reuse reluh buf0 as scratch)
    #pragma unroll
    for (int s = 1; s < 64; s <<= 1) lossAcc += __shfl_xor(lossAcc, s, 64);
    float* sred = (float*)(smem + RH_OFF);   // buf0: no longer read
    if (lane == 0) sred[wave] = lossAcc;
    __syncthreads();
    if (tid == 0) {
        float s = 0.f;
        #pragma unroll
        for (int i = 0; i < 8; ++i) s += sred[i];
        wsloss[blockIdx.x] = s;
    }
}

__global__ void loss_reduce(const float* __restrict__ wsloss, float* __restrict__ out,
                            int npart, int nelem)
{
    __shared__ float sacc[4];
    int tid = threadIdx.x;   // 256
    float v = 0.f;
    for (int j = tid; j < npart; j += 256) v += wsloss[j];   // fixed order per lane
    #pragma unroll
    for (int s = 1; s < 64; s <<= 1) v += __shfl_xor(v, s, 64);
    if ((tid & 63) == 0) sacc[tid >> 6] = v;
    __syncthreads();
    if (tid == 0) out[nelem] = (sacc[0] + sacc[1] + sacc[2] + sacc[3]) / (float)nelem;
}

extern "C" void kernel_launch(void* const* d_in, const int* in_sizes, int n_in,
                              void* d_out, int out_size, void* d_ws, size_t ws_size,
                              hipStream_t stream)
{
    const float* traj_in = (const float*)d_in[0];
    const float* traj_gt = (const float*)d_in[1];
    const float* W_ih    = (const float*)d_in[2];
    const float* W_hh    = (const float*)d_in[3];
    const float* b_ih    = (const float*)d_in[4];
    const float* b_hh    = (const float*)d_in[5];
    const float* W_last  = (const float*)d_in[6];
    const float* b_last  = (const float*)d_in[7];
    float* out = (float*)d_out;
    float* wsloss = (float*)d_ws;

    const int B      = in_sizes[0] / (OBS * 2);   // 32768
    const int blocks = B / 128;                    // 256 (2 groups of 64 rows per block)

    lstm_persist<<<blocks, 512, LDS_BYTES, stream>>>(traj_in, traj_gt, W_ih, W_hh,
                                                     b_ih, b_hh, W_last, b_last,
                                                     out, wsloss);
    loss_reduce<<<1, 256, 0, stream>>>(wsloss, out, blocks, out_size - 1);
}